// Round 10
// baseline (825.608 us; speedup 1.0000x reference)
//
#include <hip/hip_runtime.h>
#include <hip/hip_bf16.h>
#include <math.h>

#define BB 8
#define CC 64
#define NN 500
#define TT 12
#define HH 4
#define FF 64
#define CT (CC*TT)      // 768
#define HF (HH*FF)      // 256
#define NBT (HH*TT)     // 48
#define NBHT (BB*NBT)   // 384
#define NROWS (BB*HH*TT*NN)  // 192000
#define NNODE (BB*NN)   // 4000

typedef unsigned short ushort_t;
typedef unsigned int uint_t;
typedef __attribute__((ext_vector_type(8))) short short8;
typedef __attribute__((ext_vector_type(4))) float floatx4;

static __device__ __forceinline__ ushort_t f2bf(float v) {
    __hip_bfloat16 h = __float2bfloat16(v);
    ushort_t u;
    __builtin_memcpy(&u, &h, 2);
    return u;
}

// pack two f32 -> packed bf16 (lo = a, hi = b), RNE (hw v_cvt_pk on gfx950)
static __device__ __forceinline__ uint_t pkbf(float a, float b) {
    __hip_bfloat162 h = __float22bfloat162_rn(make_float2(a, b));
    uint_t u;
    __builtin_memcpy(&u, &h, 4);
    return u;
}

// ---------------------------------------------------------------------------
// K01: setup.  Blocks [0,32): bitmask[512][16 dwords]: bit k of row n =
// (adj+I)>0, zero-padded.  Blocks [32,146): p1/p2 folds, WmT, WgB=bf16(Wg).
// ---------------------------------------------------------------------------
__global__ __launch_bounds__(256) void k01_setup(const float* __restrict__ adj,
                                                 const float* __restrict__ W,
                                                 const float* __restrict__ a1,
                                                 const float* __restrict__ a2,
                                                 const float* __restrict__ Wm,
                                                 const float* __restrict__ Wg,
                                                 uint_t* __restrict__ maskbits,
                                                 float* __restrict__ p1,
                                                 float* __restrict__ p2,
                                                 float* __restrict__ WmT,
                                                 ushort_t* __restrict__ WgB) {
    int blk = blockIdx.x;
    if (blk < 32) {
        int idx = blk * 256 + threadIdx.x;   // < 512*16
        int n = idx >> 4, j = idx & 15;      // dword j covers m = j*32..+31
        uint_t v = 0;
        if (n < NN) {
            int m0 = j * 32;
            for (int i = 0; i < 32; ++i) {
                int m = m0 + i;
                bool p = (m < NN) && (adj[n*NN + m] > 0.f || m == n);
                v |= (p ? 1u : 0u) << i;
            }
        }
        maskbits[idx] = v;
        return;
    }
    int idx = (blk - 32) * 256 + threadIdx.x;
    if (idx < HH*CC) {
        int h = idx / CC, c = idx % CC;
        float s1 = 0.f, s2 = 0.f;
        for (int f = 0; f < FF; ++f) {
            float w = W[(h*CC + c)*FF + f];
            s1 += w * a1[h*FF + f];
            s2 += w * a2[h*FF + f];
        }
        p1[idx] = s1; p2[idx] = s2;
    }
    int j = idx - HH*CC;
    if (j >= 0 && j < 3*CC*CC) {
        int c = j >> 6, o = j & 63;
        WmT[j] = Wm[o*(3*CC) + c];
    }
    int j2 = idx - (HH*CC + 3*CC*CC);
    if (j2 >= 0 && j2 < FF*HF) {
        WgB[j2] = f2bf(Wg[j2]);
    }
}

// ---------------------------------------------------------------------------
// K6: transpose x [B,C,N,T] -> xT [(b*N+n)*768 + c*12 + t] (node-major).
// ---------------------------------------------------------------------------
__global__ __launch_bounds__(256) void k6_xt(const float* __restrict__ x,
                                             float* __restrict__ xT) {
    __shared__ float tile[16*776];   // 49664 B
    int b  = blockIdx.x >> 5;
    int n0 = (blockIdx.x & 31) * 16;
    for (int idx = threadIdx.x; idx < CC*16*TT; idx += 256) {
        int c   = idx / (16*TT);
        int rem = idx % (16*TT);
        int nl  = rem / TT;
        int t   = rem % TT;
        int n   = n0 + nl;
        if (n < NN)
            tile[nl*776 + c*TT + t] = x[((b*CC + c)*NN + n)*TT + t];
    }
    __syncthreads();
    for (int idx = threadIdx.x; idx < 16*CT; idx += 256) {
        int nl = idx / CT;
        int j  = idx % CT;
        int n  = n0 + nl;
        if (n < NN)
            xT[(size_t)(b*NN + n)*CT + j] = tile[nl*776 + j];
    }
}

// ---------------------------------------------------------------------------
// K2: Wh[bht][n][f] (bf16) = sum_c h[node][c,t] * W[h,c,f]; e1/e2 via p1/p2.
// f-PAIR remap: lane owns f = {2fb, 2fb+1, 2fb+32, 2fb+33} -> Wh stores are
// packed dwords (24 coalesced 4B stores vs 48 scattered 2B).
// ---------------------------------------------------------------------------
__global__ __launch_bounds__(256) void k2_wh_e(const float* __restrict__ hin,
                                               const float* __restrict__ W,
                                               const float* __restrict__ p1,
                                               const float* __restrict__ p2,
                                               ushort_t* __restrict__ Wh,
                                               float* __restrict__ e1,
                                               float* __restrict__ e2) {
    __shared__ float hL[4][CT];
    int wid  = threadIdx.x >> 6;
    int lane = threadIdx.x & 63;
    int gidx = blockIdx.x * 4 + wid;
    int b = gidx / NN, n = gidx % NN;

    {
        const float4* src = (const float4*)(hin + (size_t)gidx * CT);
        float4* dst = (float4*)hL[wid];
        for (int i = lane; i < CT/4; i += 64) dst[i] = src[i];
    }
    __syncthreads();

    const float*  hLw = hL[wid];
    const float4* h4  = (const float4*)hLw;
    int h  = lane >> 4;
    int fb = lane & 15;

    float acc[4][TT];
    #pragma unroll
    for (int q = 0; q < 4; ++q)
        #pragma unroll
        for (int t = 0; t < TT; ++t) acc[q][t] = 0.f;

    for (int c = 0; c < CC; ++c) {
        float4 v0 = h4[c*3+0], v1 = h4[c*3+1], v2 = h4[c*3+2];
        float hv[12] = {v0.x,v0.y,v0.z,v0.w, v1.x,v1.y,v1.z,v1.w,
                        v2.x,v2.y,v2.z,v2.w};
        const float* Wc = W + (h*CC + c)*FF;
        float2 wA = *(const float2*)&Wc[2*fb];
        float2 wB = *(const float2*)&Wc[2*fb + 32];
        #pragma unroll
        for (int t = 0; t < TT; ++t) {
            acc[0][t] += hv[t]*wA.x;
            acc[1][t] += hv[t]*wA.y;
            acc[2][t] += hv[t]*wB.x;
            acc[3][t] += hv[t]*wB.y;
        }
    }
    #pragma unroll
    for (int t = 0; t < TT; ++t) {
        size_t row = ((size_t)((b*HH + h)*TT + t)*NN + n)*FF;
        *(uint_t*)&Wh[row + 2*fb]      = pkbf(acc[0][t], acc[1][t]);
        *(uint_t*)&Wh[row + 2*fb + 32] = pkbf(acc[2][t], acc[3][t]);
    }

    int t2 = lane & 15;
    if (t2 < TT) {
        int h2 = lane >> 4;
        float s1 = 0.f, s2 = 0.f;
        for (int c = 0; c < CC; ++c) {
            float v = hLw[c*TT + t2];
            s1 += v * p1[h2*CC + c];
            s2 += v * p2[h2*CC + c];
        }
        int idx = ((b*HH + h2)*TT + t2)*NN + n;
        e1[idx] = s1;
        e2[idx] = s2;
    }
}

// ---------------------------------------------------------------------------
// K2T: Wh[bht][n<500][64] -> WhT[bht][f=64][m=512] bf16, m>=500 zeroed.
// ---------------------------------------------------------------------------
__global__ __launch_bounds__(256) void k2t(const ushort_t* __restrict__ Wh,
                                           ushort_t* __restrict__ WhT) {
    __shared__ ushort_t tile[32*512];     // 32 KB
    int wid  = threadIdx.x >> 6;
    int lane = threadIdx.x & 63;
    int bht  = blockIdx.x >> 1;
    int fh   = blockIdx.x & 1;            // f half: f0 = fh*32
    const ushort_t* src = Wh + (size_t)bht * NN * FF + fh*32;

    for (int task = wid; task < 32; task += 4) {
        int i  = task >> 2;               // m-block of 64 (0..7)
        int fo = task & 3;                // f-octet within half (0..3)
        int m  = i*64 + lane;
        short8 v = {0,0,0,0,0,0,0,0};
        if (m < NN) v = *(const short8*)(src + m*FF + fo*8);
        #pragma unroll
        for (int j = 0; j < 8; ++j)
            tile[(fo*8 + j)*512 + m] = (ushort_t)v[j];
    }
    __syncthreads();

    ushort_t* dst = WhT + (size_t)bht * 64 * 512 + (size_t)fh*32*512;
    for (int f = wid; f < 32; f += 4) {
        short8 v = *(const short8*)&tile[f*512 + lane*8];
        *(short8*)(dst + f*512 + lane*8) = v;
    }
}

// ---------------------------------------------------------------------------
// K3: attention PV via MFMA with LDS-staged B.
// Block = (bht, half): 768 blocks, 4 waves x 4 tiles of 16 rows.
// LDS Bs (exactly 64 KB): k-group-major [k8=c16][f][8] bf16, XOR-swizzled
// (slot = f ^ (c16&7)) -> staging writes AND b128 reads are bank-even.
// Groups 0..62 staged from WhT (coalesced); group 63 region holds e2 as
// bf16 (k>=504 has A=0 via mask bits, so the garbage B-read at ki=15/q=3 is
// annihilated).  Mask = bitmask rows (64 B/row, loaded once per tile).
// A built in registers: exp2(max(s,.2s)), s=(e1+e2)*log2e; ONES row-sum.
// ---------------------------------------------------------------------------
__global__ __launch_bounds__(256, 2) void k3_attn(const ushort_t* __restrict__ WhT,
                                                  const float* __restrict__ e1,
                                                  const float* __restrict__ e2,
                                                  const uint_t* __restrict__ maskbits,
                                                  ushort_t* __restrict__ hprB) {
    __shared__ ushort_t Bs[64*512];       // 65536 B exactly
    ushort_t* e2b = Bs + 63*512;          // bf16 e2 (512 entries, 1024 B)
    int tid  = threadIdx.x;
    int wid  = tid >> 6;
    int lane = tid & 63;
    int bht  = blockIdx.x >> 1;
    int half = blockIdx.x & 1;
    int b    = bht / NBT;
    int ht   = bht % NBT;

    const float* e1p = e1 + (size_t)bht * NN;
    const float* e2p = e2 + (size_t)bht * NN;
    const float L2E = 1.4426950408889634f;

    {   // stage WhT slice -> swizzled LDS (k-groups 0..62) + e2 bf16
        const ushort_t* WT = WhT + (size_t)bht * 64 * 512;
        int c16   = tid & 63;
        int fbase = tid >> 6;
        if (c16 < 63) {
            #pragma unroll
            for (int rr = 0; rr < 16; ++rr) {
                int f = fbase + rr*4;
                short8 v = *(const short8*)(WT + (size_t)f*512 + c16*8);
                *(short8*)&Bs[c16*512 + ((f ^ (c16 & 7)) << 3)] = v;
            }
        }
        for (int i = tid; i < 512; i += 256) {
            float e = (i < NN) ? e2p[i] * L2E : 0.f;
            e2b[i] = f2bf(e);
        }
    }
    __syncthreads();

    int quad = lane >> 4;                 // 0..3
    int r    = lane & 15;                 // A-row / C-col

    const short8 ONES = {0x3F80,0x3F80,0x3F80,0x3F80,
                         0x3F80,0x3F80,0x3F80,0x3F80}; // bf16 1.0 x8

    for (int u = 0; u < 4; ++u) {
        int n0 = half*256 + (wid*4 + u)*16;
        int nrow = n0 + r;                // < 512
        float e1v = ((nrow < NN) ? e1p[nrow] : 0.f) * L2E;

        // bitmask row: 64 B, 4 x uint4
        const uint_t* mrow = maskbits + nrow*16;
        uint4 mq0 = *(const uint4*)(mrow);
        uint4 mq1 = *(const uint4*)(mrow + 4);
        uint4 mq2 = *(const uint4*)(mrow + 8);
        uint4 mq3 = *(const uint4*)(mrow + 12);
        uint_t mk[16] = {mq0.x,mq0.y,mq0.z,mq0.w, mq1.x,mq1.y,mq1.z,mq1.w,
                         mq2.x,mq2.y,mq2.z,mq2.w, mq3.x,mq3.y,mq3.z,mq3.w};

        floatx4 C[4];
        floatx4 Cs = {0.f,0.f,0.f,0.f};
        #pragma unroll
        for (int ft = 0; ft < 4; ++ft) C[ft] = (floatx4){0.f,0.f,0.f,0.f};

        #pragma unroll
        for (int ki = 0; ki < 16; ++ki) {
            int cc = ki*4 + quad;
            int rx = r ^ (cc & 7);
            const ushort_t* bp = &Bs[cc*512 + rx*8];
            short8 b0 = *(const short8*)(bp);
            short8 b1 = *(const short8*)(bp + 128);
            short8 b2 = *(const short8*)(bp + 256);
            short8 b3 = *(const short8*)(bp + 384);

            // e2 octet (bf16 -> f32)
            union { short8 s; uint_t u[4]; } ev8;
            ev8.s = *(const short8*)&e2b[ki*32 + quad*8];
            float ev[8];
            #pragma unroll
            for (int d = 0; d < 4; ++d) {
                ev[2*d]   = __uint_as_float(ev8.u[d] << 16);
                ev[2*d+1] = __uint_as_float(ev8.u[d] & 0xffff0000u);
            }

            uint_t mbits = mk[ki] >> (quad*8);
            union { uint_t u[4]; short8 s; } av;
            #pragma unroll
            for (int p = 0; p < 4; ++p) {
                float s0 = e1v + ev[2*p];
                float s1 = e1v + ev[2*p+1];
                float g0 = fmaxf(s0, 0.2f*s0);
                float g1 = fmaxf(s1, 0.2f*s1);
                float x0 = __builtin_amdgcn_exp2f(g0);
                float x1 = __builtin_amdgcn_exp2f(g1);
                x0 = (mbits & (1u << (2*p)))     ? x0 : 0.f;
                x1 = (mbits & (1u << (2*p + 1))) ? x1 : 0.f;
                av.u[p] = pkbf(x0, x1);
            }
            C[0] = __builtin_amdgcn_mfma_f32_16x16x32_bf16(av.s, b0, C[0], 0, 0, 0);
            C[1] = __builtin_amdgcn_mfma_f32_16x16x32_bf16(av.s, b1, C[1], 0, 0, 0);
            C[2] = __builtin_amdgcn_mfma_f32_16x16x32_bf16(av.s, b2, C[2], 0, 0, 0);
            C[3] = __builtin_amdgcn_mfma_f32_16x16x32_bf16(av.s, b3, C[3], 0, 0, 0);
            Cs   = __builtin_amdgcn_mfma_f32_16x16x32_bf16(av.s, ONES, Cs, 0, 0, 0);
        }

        // epilogue: scale by 1/lsum, ELU, store bf16 node-major
        #pragma unroll
        for (int reg = 0; reg < 4; ++reg) {
            int row = quad*4 + reg;
            int n = n0 + row;
            if (n < NN) {
                float inv = 1.0f / Cs[reg];
                size_t base = ((size_t)(b*NN + n)*NBT + ht)*FF;
                #pragma unroll
                for (int ft = 0; ft < 4; ++ft) {
                    float v = C[ft][reg] * inv;
                    v = v > 0.f ? v : __expf(v) - 1.f;
                    hprB[base + ft*16 + r] = f2bf(v);
                }
            }
        }
    }
}

// ---------------------------------------------------------------------------
// K4: head-mix 1x1 conv + residual via MFMA.  1 node per WAVE, 1000 blocks.
// ---------------------------------------------------------------------------
__global__ __launch_bounds__(256) void k4_mfma(const ushort_t* __restrict__ hprB,
                                               const ushort_t* __restrict__ WgB,
                                               const float* __restrict__ bg,
                                               const float* __restrict__ xT,
                                               float* __restrict__ hnext) {
    int wid  = threadIdx.x >> 6;
    int lane = threadIdx.x & 63;
    int quad = lane >> 4;
    int r    = lane & 15;

    short8 Afr[4][8];
    #pragma unroll
    for (int ot = 0; ot < 4; ++ot)
        #pragma unroll
        for (int kc = 0; kc < 8; ++kc)
            Afr[ot][kc] = *(const short8*)(WgB + (size_t)(ot*16 + r)*HF + kc*32 + quad*8);

    float4 bgv[4];
    #pragma unroll
    for (int ot = 0; ot < 4; ++ot)
        bgv[ot] = *(const float4*)(bg + ot*16 + quad*4);

    int tcl = r < TT ? r : TT-1;

    int node = blockIdx.x*4 + wid;
    const ushort_t* P = hprB + (size_t)node * (NBT*FF);

    floatx4 C[4];
    #pragma unroll
    for (int ot = 0; ot < 4; ++ot) C[ot] = (floatx4){0.f,0.f,0.f,0.f};

    #pragma unroll
    for (int kc = 0; kc < 8; ++kc) {
        int k = kc*32 + quad*8;
        int h = k >> 6, f0 = k & 63;
        short8 bfr = *(const short8*)(P + (h*TT + tcl)*FF + f0);
        #pragma unroll
        for (int ot = 0; ot < 4; ++ot)
            C[ot] = __builtin_amdgcn_mfma_f32_16x16x32_bf16(Afr[ot][kc], bfr, C[ot], 0, 0, 0);
    }

    if (r < TT) {
        float* hout = hnext + (size_t)node * CT;
        const float* xp = xT + (size_t)node * CT;
        #pragma unroll
        for (int ot = 0; ot < 4; ++ot) {
            #pragma unroll
            for (int reg = 0; reg < 4; ++reg) {
                int o = ot*16 + quad*4 + reg;
                float v = C[ot][reg] + bgv[ot][reg];
                hout[o*TT + r] = 0.05f*xp[o*TT + r] + 0.95f*v;
            }
        }
    }
}

// ---------------------------------------------------------------------------
// K45: fused layer-2 head-mix + final mix.  1 node per WAVE, 1000 blocks.
// ---------------------------------------------------------------------------
__global__ __launch_bounds__(256) void k45_fused(const ushort_t* __restrict__ hprB,
                                                 const ushort_t* __restrict__ WgB,
                                                 const float* __restrict__ bg,
                                                 const float* __restrict__ xT,
                                                 const float* __restrict__ h1,
                                                 const float* __restrict__ WmT,
                                                 const float* __restrict__ bm,
                                                 float* __restrict__ out) {
    __shared__ float S[4][3][CT];         // 36864 B: [wid][x|h1|h2]
    int wid  = threadIdx.x >> 6;
    int lane = threadIdx.x & 63;
    int quad = lane >> 4;
    int r    = lane & 15;

    int node = blockIdx.x*4 + wid;
    int b = node / NN, n = node % NN;

    {   // stage x, h1 (coalesced, wave-private)
        const float4* sx = (const float4*)(xT + (size_t)node*CT);
        const float4* sh = (const float4*)(h1 + (size_t)node*CT);
        float4* d0 = (float4*)S[wid][0];
        float4* d1 = (float4*)S[wid][1];
        for (int i = lane; i < CT/4; i += 64) { d0[i] = sx[i]; d1[i] = sh[i]; }
    }

    // ---- k4 body: h2 = 0.05x + 0.95(Wg @ hpr + bg) ----
    short8 Afr[4][8];
    #pragma unroll
    for (int ot = 0; ot < 4; ++ot)
        #pragma unroll
        for (int kc = 0; kc < 8; ++kc)
            Afr[ot][kc] = *(const short8*)(WgB + (size_t)(ot*16 + r)*HF + kc*32 + quad*8);
    float4 bgv[4];
    #pragma unroll
    for (int ot = 0; ot < 4; ++ot)
        bgv[ot] = *(const float4*)(bg + ot*16 + quad*4);

    int tcl = r < TT ? r : TT-1;
    const ushort_t* P = hprB + (size_t)node * (NBT*FF);

    floatx4 C[4];
    #pragma unroll
    for (int ot = 0; ot < 4; ++ot) C[ot] = (floatx4){0.f,0.f,0.f,0.f};
    #pragma unroll
    for (int kc = 0; kc < 8; ++kc) {
        int k = kc*32 + quad*8;
        int h = k >> 6, f0 = k & 63;
        short8 bfr = *(const short8*)(P + (h*TT + tcl)*FF + f0);
        #pragma unroll
        for (int ot = 0; ot < 4; ++ot)
            C[ot] = __builtin_amdgcn_mfma_f32_16x16x32_bf16(Afr[ot][kc], bfr, C[ot], 0, 0, 0);
    }

    if (r < TT) {   // h2 -> wave-private LDS
        #pragma unroll
        for (int ot = 0; ot < 4; ++ot) {
            #pragma unroll
            for (int reg = 0; reg < 4; ++reg) {
                int o = ot*16 + quad*4 + reg;
                float v = C[ot][reg] + bgv[ot][reg];
                S[wid][2][o*TT + r] = 0.05f*S[wid][0][o*TT + r] + 0.95f*v;
            }
        }
    }

    // ---- k5 body: out = bm + Wm @ [x|h1|h2] ----
    float (*Sw)[CT] = S[wid];
    int ob = lane & 15;
    int tq = lane >> 4;

    float acc[4][3];
    #pragma unroll
    for (int oi = 0; oi < 4; ++oi) {
        float bv = bm[ob + 16*oi];
        #pragma unroll
        for (int ti = 0; ti < 3; ++ti) acc[oi][ti] = bv;
    }

    for (int c = 0; c < CC; ++c) {
        float v0[3], v1[3], v2[3];
        #pragma unroll
        for (int ti = 0; ti < 3; ++ti) {
            int t = tq + 4*ti;
            v0[ti] = Sw[0][c*TT + t];
            v1[ti] = Sw[1][c*TT + t];
            v2[ti] = Sw[2][c*TT + t];
        }
        #pragma unroll
        for (int oi = 0; oi < 4; ++oi) {
            int o = ob + 16*oi;
            float w0 = WmT[(c       )*64 + o];
            float w1 = WmT[(CC  + c )*64 + o];
            float w2 = WmT[(2*CC + c)*64 + o];
            #pragma unroll
            for (int ti = 0; ti < 3; ++ti) {
                acc[oi][ti] += v0[ti]*w0 + v1[ti]*w1 + v2[ti]*w2;
            }
        }
    }

    #pragma unroll
    for (int oi = 0; oi < 4; ++oi) {
        int o = ob + 16*oi;
        #pragma unroll
        for (int ti = 0; ti < 3; ++ti) {
            int t = tq + 4*ti;
            out[((b*CC + o)*NN + n)*TT + t] = acc[oi][ti];
        }
    }
}

// ---------------------------------------------------------------------------
extern "C" void kernel_launch(void* const* d_in, const int* in_sizes, int n_in,
                              void* d_out, int out_size, void* d_ws, size_t ws_size,
                              hipStream_t stream) {
    const float* x   = (const float*)d_in[0];
    const float* adj = (const float*)d_in[1];
    const float* W   = (const float*)d_in[2];
    const float* a1  = (const float*)d_in[3];
    const float* a2  = (const float*)d_in[4];
    const float* Wg  = (const float*)d_in[5];
    const float* bg  = (const float*)d_in[6];
    const float* Wm  = (const float*)d_in[7];
    const float* bm  = (const float*)d_in[8];
    float* out = (float*)d_out;

    char* ws = (char*)d_ws;
    size_t off = 0;
    auto alloc = [&](size_t bytes) -> void* {
        void* p = ws + off;
        off += (bytes + 255) & ~(size_t)255;
        return p;
    };

    uint_t* maskbits = (uint_t*)alloc((size_t)512 * 16 * 4);                // 32 KB
    float* p1   = (float*)alloc(HH*CC * sizeof(float));
    float* p2   = (float*)alloc(HH*CC * sizeof(float));
    float* WmT  = (float*)alloc(3*CC*CC * sizeof(float));
    ushort_t* WgB = (ushort_t*)alloc((size_t)FF*HF * 2);
    float* xT   = (float*)alloc((size_t)NNODE * CT * sizeof(float));        // 12.3 MB
    ushort_t* Wh   = (ushort_t*)alloc((size_t)NROWS * FF * 2);              // 24.6 MB
    ushort_t* WhT  = (ushort_t*)alloc((size_t)NBHT * 64 * 512 * 2);         // 25.2 MB
    ushort_t* hprB = (ushort_t*)alloc((size_t)NNODE * NBT * FF * 2);        // 24.6 MB
    float* e1   = (float*)alloc((size_t)NROWS * sizeof(float));
    float* e2   = (float*)alloc((size_t)NROWS * sizeof(float));
    float* h1   = (float*)alloc((size_t)NNODE * CT * sizeof(float));        // 12.3 MB
    (void)ws_size;

    k01_setup<<<146, 256, 0, stream>>>(adj, W, a1, a2, Wm, Wg,
                                       maskbits, p1, p2, WmT, WgB);
    k6_xt    <<<256, 256, 0, stream>>>(x, xT);

    // layer 1
    k2_wh_e <<<NNODE/4, 256, 0, stream>>>(xT, W, p1, p2, Wh, e1, e2);
    k2t     <<<NBHT*2,  256, 0, stream>>>(Wh, WhT);
    k3_attn <<<NBHT*2,  256, 0, stream>>>(WhT, e1, e2, maskbits, hprB);
    k4_mfma <<<NNODE/4, 256, 0, stream>>>(hprB, WgB, bg, xT, h1);

    // layer 2
    k2_wh_e <<<NNODE/4, 256, 0, stream>>>(h1, W, p1, p2, Wh, e1, e2);
    k2t     <<<NBHT*2,  256, 0, stream>>>(Wh, WhT);
    k3_attn <<<NBHT*2,  256, 0, stream>>>(WhT, e1, e2, maskbits, hprB);

    // fused layer-2 mix + final
    k45_fused<<<NNODE/4, 256, 0, stream>>>(hprB, WgB, bg, xT, h1, WmT, bm, out);
}

// Round 11
// 343.845 us; speedup vs baseline: 2.4011x; 2.4011x over previous
//
#include <hip/hip_runtime.h>
#include <hip/hip_bf16.h>
#include <math.h>

#define BB 8
#define CC 64
#define NN 500
#define TT 12
#define HH 4
#define FF 64
#define CT (CC*TT)      // 768
#define HF (HH*FF)      // 256
#define NBT (HH*TT)     // 48
#define NBHT (BB*NBT)   // 384
#define NROWS (BB*HH*TT*NN)  // 192000
#define NNODE (BB*NN)   // 4000

typedef unsigned short ushort_t;
typedef unsigned int uint_t;
typedef __attribute__((ext_vector_type(8))) short short8;
typedef __attribute__((ext_vector_type(4))) float floatx4;

static __device__ __forceinline__ ushort_t f2bf(float v) {
    __hip_bfloat16 h = __float2bfloat16(v);
    ushort_t u;
    __builtin_memcpy(&u, &h, 2);
    return u;
}

// pack two f32 -> packed bf16 (lo = a, hi = b), RNE (hw v_cvt_pk on gfx950)
static __device__ __forceinline__ uint_t pkbf(float a, float b) {
    __hip_bfloat162 h = __float22bfloat162_rn(make_float2(a, b));
    uint_t u;
    __builtin_memcpy(&u, &h, 4);
    return u;
}

// ---------------------------------------------------------------------------
// K01: setup.  Blocks [0,32): bitmask[512][16 dwords]: bit k of row n =
// (adj+I)>0, zero-padded.  Blocks [32,146): p1/p2 folds, WmT, WgB=bf16(Wg).
// ---------------------------------------------------------------------------
__global__ __launch_bounds__(256) void k01_setup(const float* __restrict__ adj,
                                                 const float* __restrict__ W,
                                                 const float* __restrict__ a1,
                                                 const float* __restrict__ a2,
                                                 const float* __restrict__ Wm,
                                                 const float* __restrict__ Wg,
                                                 uint_t* __restrict__ maskbits,
                                                 float* __restrict__ p1,
                                                 float* __restrict__ p2,
                                                 float* __restrict__ WmT,
                                                 ushort_t* __restrict__ WgB) {
    int blk = blockIdx.x;
    if (blk < 32) {
        int idx = blk * 256 + threadIdx.x;   // < 512*16
        int n = idx >> 4, j = idx & 15;      // dword j covers m = j*32..+31
        uint_t v = 0;
        if (n < NN) {
            int m0 = j * 32;
            for (int i = 0; i < 32; ++i) {
                int m = m0 + i;
                bool p = (m < NN) && (adj[n*NN + m] > 0.f || m == n);
                v |= (p ? 1u : 0u) << i;
            }
        }
        maskbits[idx] = v;
        return;
    }
    int idx = (blk - 32) * 256 + threadIdx.x;
    if (idx < HH*CC) {
        int h = idx / CC, c = idx % CC;
        float s1 = 0.f, s2 = 0.f;
        for (int f = 0; f < FF; ++f) {
            float w = W[(h*CC + c)*FF + f];
            s1 += w * a1[h*FF + f];
            s2 += w * a2[h*FF + f];
        }
        p1[idx] = s1; p2[idx] = s2;
    }
    int j = idx - HH*CC;
    if (j >= 0 && j < 3*CC*CC) {
        int c = j >> 6, o = j & 63;
        WmT[j] = Wm[o*(3*CC) + c];
    }
    int j2 = idx - (HH*CC + 3*CC*CC);
    if (j2 >= 0 && j2 < FF*HF) {
        WgB[j2] = f2bf(Wg[j2]);
    }
}

// ---------------------------------------------------------------------------
// K6: transpose x [B,C,N,T] -> xT [(b*N+n)*768 + c*12 + t] (node-major).
// ---------------------------------------------------------------------------
__global__ __launch_bounds__(256) void k6_xt(const float* __restrict__ x,
                                             float* __restrict__ xT) {
    __shared__ float tile[16*776];   // 49664 B
    int b  = blockIdx.x >> 5;
    int n0 = (blockIdx.x & 31) * 16;
    for (int idx = threadIdx.x; idx < CC*16*TT; idx += 256) {
        int c   = idx / (16*TT);
        int rem = idx % (16*TT);
        int nl  = rem / TT;
        int t   = rem % TT;
        int n   = n0 + nl;
        if (n < NN)
            tile[nl*776 + c*TT + t] = x[((b*CC + c)*NN + n)*TT + t];
    }
    __syncthreads();
    for (int idx = threadIdx.x; idx < 16*CT; idx += 256) {
        int nl = idx / CT;
        int j  = idx % CT;
        int n  = n0 + nl;
        if (n < NN)
            xT[(size_t)(b*NN + n)*CT + j] = tile[nl*776 + j];
    }
}

// ---------------------------------------------------------------------------
// K2: Wh[bht][n][f] (bf16) = sum_c h[node][c,t] * W[h,c,f]; e1/e2 via p1/p2.
// f-PAIR remap -> packed dword Wh stores.
// ---------------------------------------------------------------------------
__global__ __launch_bounds__(256) void k2_wh_e(const float* __restrict__ hin,
                                               const float* __restrict__ W,
                                               const float* __restrict__ p1,
                                               const float* __restrict__ p2,
                                               ushort_t* __restrict__ Wh,
                                               float* __restrict__ e1,
                                               float* __restrict__ e2) {
    __shared__ float hL[4][CT];
    int wid  = threadIdx.x >> 6;
    int lane = threadIdx.x & 63;
    int gidx = blockIdx.x * 4 + wid;
    int b = gidx / NN, n = gidx % NN;

    {
        const float4* src = (const float4*)(hin + (size_t)gidx * CT);
        float4* dst = (float4*)hL[wid];
        for (int i = lane; i < CT/4; i += 64) dst[i] = src[i];
    }
    __syncthreads();

    const float*  hLw = hL[wid];
    const float4* h4  = (const float4*)hLw;
    int h  = lane >> 4;
    int fb = lane & 15;

    float acc[4][TT];
    #pragma unroll
    for (int q = 0; q < 4; ++q)
        #pragma unroll
        for (int t = 0; t < TT; ++t) acc[q][t] = 0.f;

    for (int c = 0; c < CC; ++c) {
        float4 v0 = h4[c*3+0], v1 = h4[c*3+1], v2 = h4[c*3+2];
        float hv[12] = {v0.x,v0.y,v0.z,v0.w, v1.x,v1.y,v1.z,v1.w,
                        v2.x,v2.y,v2.z,v2.w};
        const float* Wc = W + (h*CC + c)*FF;
        float2 wA = *(const float2*)&Wc[2*fb];
        float2 wB = *(const float2*)&Wc[2*fb + 32];
        #pragma unroll
        for (int t = 0; t < TT; ++t) {
            acc[0][t] += hv[t]*wA.x;
            acc[1][t] += hv[t]*wA.y;
            acc[2][t] += hv[t]*wB.x;
            acc[3][t] += hv[t]*wB.y;
        }
    }
    #pragma unroll
    for (int t = 0; t < TT; ++t) {
        size_t row = ((size_t)((b*HH + h)*TT + t)*NN + n)*FF;
        *(uint_t*)&Wh[row + 2*fb]      = pkbf(acc[0][t], acc[1][t]);
        *(uint_t*)&Wh[row + 2*fb + 32] = pkbf(acc[2][t], acc[3][t]);
    }

    int t2 = lane & 15;
    if (t2 < TT) {
        int h2 = lane >> 4;
        float s1 = 0.f, s2 = 0.f;
        for (int c = 0; c < CC; ++c) {
            float v = hLw[c*TT + t2];
            s1 += v * p1[h2*CC + c];
            s2 += v * p2[h2*CC + c];
        }
        int idx = ((b*HH + h2)*TT + t2)*NN + n;
        e1[idx] = s1;
        e2[idx] = s2;
    }
}

// ---------------------------------------------------------------------------
// K2T: Wh[bht][n<500][64] -> WhT[bht][f=64][m=512] bf16, m>=500 zeroed.
// ---------------------------------------------------------------------------
__global__ __launch_bounds__(256) void k2t(const ushort_t* __restrict__ Wh,
                                           ushort_t* __restrict__ WhT) {
    __shared__ ushort_t tile[32*512];     // 32 KB
    int wid  = threadIdx.x >> 6;
    int lane = threadIdx.x & 63;
    int bht  = blockIdx.x >> 1;
    int fh   = blockIdx.x & 1;            // f half: f0 = fh*32
    const ushort_t* src = Wh + (size_t)bht * NN * FF + fh*32;

    for (int task = wid; task < 32; task += 4) {
        int i  = task >> 2;               // m-block of 64 (0..7)
        int fo = task & 3;                // f-octet within half (0..3)
        int m  = i*64 + lane;
        short8 v = {0,0,0,0,0,0,0,0};
        if (m < NN) v = *(const short8*)(src + m*FF + fo*8);
        #pragma unroll
        for (int j = 0; j < 8; ++j)
            tile[(fo*8 + j)*512 + m] = (ushort_t)v[j];
    }
    __syncthreads();

    ushort_t* dst = WhT + (size_t)bht * 64 * 512 + (size_t)fh*32*512;
    for (int f = wid; f < 32; f += 4) {
        short8 v = *(const short8*)&tile[f*512 + lane*8];
        *(short8*)(dst + f*512 + lane*8) = v;
    }
}

// ---------------------------------------------------------------------------
// K3: attention PV via MFMA — R7 structure (direct global B-frag loads,
// register-built A, inline exp2, hw bf16 pack), extended to 4 tiles/wave so
// each scattered B-load is shared by 4 tiles (R7 had 2).  Per-ki mask loads
// replaced by LDS bitmask rows (16 dwords/row padded to 17; staged once per
// block; reads are 16-row broadcast, conflict-free: (17r+ki)%32 distinct).
// Block = (bht, half): 768 blocks, 4 waves x 4 tiles x 16 rows.
// Shift-free softmax; ONES row-sum; launch_bounds(256,3) -> no spill.
// ---------------------------------------------------------------------------
__global__ __launch_bounds__(256, 3) void k3_attn(const ushort_t* __restrict__ WhT,
                                                  const float* __restrict__ e1,
                                                  const float* __restrict__ e2,
                                                  const uint_t* __restrict__ maskbits,
                                                  ushort_t* __restrict__ hprB) {
    __shared__ float  e2s[512];           // 2 KB
    __shared__ uint_t mks[256*17];        // 17408 B (block-local rows, padded)
    int tid  = threadIdx.x;
    int wid  = tid >> 6;
    int lane = tid & 63;
    int bht  = blockIdx.x >> 1;           // consecutive blocks share bht (L2)
    int half = blockIdx.x & 1;
    int b    = bht / NBT;
    int ht   = bht % NBT;

    const float* e1p = e1 + (size_t)bht * NN;
    const float* e2p = e2 + (size_t)bht * NN;
    const ushort_t* WT = WhT + (size_t)bht * 64 * 512;
    const float L2E = 1.4426950408889634f;

    {
        int i = tid;
        e2s[i] = (i < NN) ? e2p[i] * L2E : 0.f;
        i = tid + 256;
        e2s[i] = (i < NN) ? e2p[i] * L2E : 0.f;
    }
    for (int i = tid; i < 256*16; i += 256) {
        int rl = i >> 4, dw = i & 15;
        mks[rl*17 + dw] = maskbits[(half*256 + rl)*16 + dw];
    }
    __syncthreads();

    int quad = lane >> 4;                 // 0..3
    int r    = lane & 15;                 // A-row / C-col

    const short8 ONES = {0x3F80,0x3F80,0x3F80,0x3F80,
                         0x3F80,0x3F80,0x3F80,0x3F80}; // bf16 1.0 x8

    // per-tile e1 (pre-scaled); tile u rows: half*256 + (wid*4+u)*16 + r
    float e1v[4];
    #pragma unroll
    for (int u = 0; u < 4; ++u) {
        int nrow = half*256 + (wid*4 + u)*16 + r;
        e1v[u] = ((nrow < NN) ? e1p[nrow] : 0.f) * L2E;
    }
    int rl0 = wid*64 + r;                 // block-local row of tile 0

    const ushort_t* WTr = WT + (size_t)r * 512;   // + ft*8192 + kb

    floatx4 C[4][4];
    floatx4 Cs[4];
    #pragma unroll
    for (int u = 0; u < 4; ++u) {
        Cs[u] = (floatx4){0.f,0.f,0.f,0.f};
        #pragma unroll
        for (int ft = 0; ft < 4; ++ft) C[u][ft] = (floatx4){0.f,0.f,0.f,0.f};
    }

    #pragma unroll
    for (int ki = 0; ki < 16; ++ki) {
        int kb = ki*32 + quad*8;

        short8 b0 = *(const short8*)(WTr + 0*8192 + kb);
        short8 b1 = *(const short8*)(WTr + 1*8192 + kb);
        short8 b2 = *(const short8*)(WTr + 2*8192 + kb);
        short8 b3 = *(const short8*)(WTr + 3*8192 + kb);

        float4 ea = *(const float4*)&e2s[kb];
        float4 eb = *(const float4*)&e2s[kb + 4];
        float ev[8] = {ea.x,ea.y,ea.z,ea.w, eb.x,eb.y,eb.z,eb.w};

        #pragma unroll
        for (int u = 0; u < 4; ++u) {
            uint_t md    = mks[(rl0 + u*16)*17 + ki];  // bits m=ki*32..+31
            uint_t mbits = md >> (quad*8);
            union { uint_t w[4]; short8 s; } av;
            #pragma unroll
            for (int p = 0; p < 4; ++p) {
                float s0 = e1v[u] + ev[2*p];
                float s1 = e1v[u] + ev[2*p+1];
                float g0 = fmaxf(s0, 0.2f*s0);
                float g1 = fmaxf(s1, 0.2f*s1);
                float x0 = __builtin_amdgcn_exp2f(g0);
                float x1 = __builtin_amdgcn_exp2f(g1);
                x0 = (mbits & (1u << (2*p)))     ? x0 : 0.f;
                x1 = (mbits & (1u << (2*p + 1))) ? x1 : 0.f;
                av.w[p] = pkbf(x0, x1);
            }
            C[u][0] = __builtin_amdgcn_mfma_f32_16x16x32_bf16(av.s, b0, C[u][0], 0, 0, 0);
            C[u][1] = __builtin_amdgcn_mfma_f32_16x16x32_bf16(av.s, b1, C[u][1], 0, 0, 0);
            C[u][2] = __builtin_amdgcn_mfma_f32_16x16x32_bf16(av.s, b2, C[u][2], 0, 0, 0);
            C[u][3] = __builtin_amdgcn_mfma_f32_16x16x32_bf16(av.s, b3, C[u][3], 0, 0, 0);
            Cs[u]   = __builtin_amdgcn_mfma_f32_16x16x32_bf16(av.s, ONES, Cs[u], 0, 0, 0);
        }
    }

    // epilogue: scale by 1/lsum, ELU, store bf16 node-major
    #pragma unroll
    for (int u = 0; u < 4; ++u) {
        int n0 = half*256 + (wid*4 + u)*16;
        #pragma unroll
        for (int reg = 0; reg < 4; ++reg) {
            int n = n0 + quad*4 + reg;
            if (n < NN) {
                float inv = 1.0f / Cs[u][reg];
                size_t base = ((size_t)(b*NN + n)*NBT + ht)*FF;
                #pragma unroll
                for (int ft = 0; ft < 4; ++ft) {
                    float v = C[u][ft][reg] * inv;
                    v = v > 0.f ? v : __expf(v) - 1.f;
                    hprB[base + ft*16 + r] = f2bf(v);
                }
            }
        }
    }
}

// ---------------------------------------------------------------------------
// K4: head-mix 1x1 conv + residual via MFMA.  1 node per WAVE, 1000 blocks.
// ---------------------------------------------------------------------------
__global__ __launch_bounds__(256) void k4_mfma(const ushort_t* __restrict__ hprB,
                                               const ushort_t* __restrict__ WgB,
                                               const float* __restrict__ bg,
                                               const float* __restrict__ xT,
                                               float* __restrict__ hnext) {
    int wid  = threadIdx.x >> 6;
    int lane = threadIdx.x & 63;
    int quad = lane >> 4;
    int r    = lane & 15;

    short8 Afr[4][8];
    #pragma unroll
    for (int ot = 0; ot < 4; ++ot)
        #pragma unroll
        for (int kc = 0; kc < 8; ++kc)
            Afr[ot][kc] = *(const short8*)(WgB + (size_t)(ot*16 + r)*HF + kc*32 + quad*8);

    float4 bgv[4];
    #pragma unroll
    for (int ot = 0; ot < 4; ++ot)
        bgv[ot] = *(const float4*)(bg + ot*16 + quad*4);

    int tcl = r < TT ? r : TT-1;

    int node = blockIdx.x*4 + wid;
    const ushort_t* P = hprB + (size_t)node * (NBT*FF);

    floatx4 C[4];
    #pragma unroll
    for (int ot = 0; ot < 4; ++ot) C[ot] = (floatx4){0.f,0.f,0.f,0.f};

    #pragma unroll
    for (int kc = 0; kc < 8; ++kc) {
        int k = kc*32 + quad*8;
        int h = k >> 6, f0 = k & 63;
        short8 bfr = *(const short8*)(P + (h*TT + tcl)*FF + f0);
        #pragma unroll
        for (int ot = 0; ot < 4; ++ot)
            C[ot] = __builtin_amdgcn_mfma_f32_16x16x32_bf16(Afr[ot][kc], bfr, C[ot], 0, 0, 0);
    }

    if (r < TT) {
        float* hout = hnext + (size_t)node * CT;
        const float* xp = xT + (size_t)node * CT;
        #pragma unroll
        for (int ot = 0; ot < 4; ++ot) {
            #pragma unroll
            for (int reg = 0; reg < 4; ++reg) {
                int o = ot*16 + quad*4 + reg;
                float v = C[ot][reg] + bgv[ot][reg];
                hout[o*TT + r] = 0.05f*xp[o*TT + r] + 0.95f*v;
            }
        }
    }
}

// ---------------------------------------------------------------------------
// K45: fused layer-2 head-mix + final mix.  1 node per WAVE, 1000 blocks.
// ---------------------------------------------------------------------------
__global__ __launch_bounds__(256) void k45_fused(const ushort_t* __restrict__ hprB,
                                                 const ushort_t* __restrict__ WgB,
                                                 const float* __restrict__ bg,
                                                 const float* __restrict__ xT,
                                                 const float* __restrict__ h1,
                                                 const float* __restrict__ WmT,
                                                 const float* __restrict__ bm,
                                                 float* __restrict__ out) {
    __shared__ float S[4][3][CT];         // 36864 B: [wid][x|h1|h2]
    int wid  = threadIdx.x >> 6;
    int lane = threadIdx.x & 63;
    int quad = lane >> 4;
    int r    = lane & 15;

    int node = blockIdx.x*4 + wid;
    int b = node / NN, n = node % NN;

    {   // stage x, h1 (coalesced, wave-private)
        const float4* sx = (const float4*)(xT + (size_t)node*CT);
        const float4* sh = (const float4*)(h1 + (size_t)node*CT);
        float4* d0 = (float4*)S[wid][0];
        float4* d1 = (float4*)S[wid][1];
        for (int i = lane; i < CT/4; i += 64) { d0[i] = sx[i]; d1[i] = sh[i]; }
    }

    // ---- k4 body: h2 = 0.05x + 0.95(Wg @ hpr + bg) ----
    short8 Afr[4][8];
    #pragma unroll
    for (int ot = 0; ot < 4; ++ot)
        #pragma unroll
        for (int kc = 0; kc < 8; ++kc)
            Afr[ot][kc] = *(const short8*)(WgB + (size_t)(ot*16 + r)*HF + kc*32 + quad*8);
    float4 bgv[4];
    #pragma unroll
    for (int ot = 0; ot < 4; ++ot)
        bgv[ot] = *(const float4*)(bg + ot*16 + quad*4);

    int tcl = r < TT ? r : TT-1;
    const ushort_t* P = hprB + (size_t)node * (NBT*FF);

    floatx4 C[4];
    #pragma unroll
    for (int ot = 0; ot < 4; ++ot) C[ot] = (floatx4){0.f,0.f,0.f,0.f};
    #pragma unroll
    for (int kc = 0; kc < 8; ++kc) {
        int k = kc*32 + quad*8;
        int h = k >> 6, f0 = k & 63;
        short8 bfr = *(const short8*)(P + (h*TT + tcl)*FF + f0);
        #pragma unroll
        for (int ot = 0; ot < 4; ++ot)
            C[ot] = __builtin_amdgcn_mfma_f32_16x16x32_bf16(Afr[ot][kc], bfr, C[ot], 0, 0, 0);
    }

    if (r < TT) {   // h2 -> wave-private LDS
        #pragma unroll
        for (int ot = 0; ot < 4; ++ot) {
            #pragma unroll
            for (int reg = 0; reg < 4; ++reg) {
                int o = ot*16 + quad*4 + reg;
                float v = C[ot][reg] + bgv[ot][reg];
                S[wid][2][o*TT + r] = 0.05f*S[wid][0][o*TT + r] + 0.95f*v;
            }
        }
    }

    // ---- k5 body: out = bm + Wm @ [x|h1|h2] ----
    float (*Sw)[CT] = S[wid];
    int ob = lane & 15;
    int tq = lane >> 4;

    float acc[4][3];
    #pragma unroll
    for (int oi = 0; oi < 4; ++oi) {
        float bv = bm[ob + 16*oi];
        #pragma unroll
        for (int ti = 0; ti < 3; ++ti) acc[oi][ti] = bv;
    }

    for (int c = 0; c < CC; ++c) {
        float v0[3], v1[3], v2[3];
        #pragma unroll
        for (int ti = 0; ti < 3; ++ti) {
            int t = tq + 4*ti;
            v0[ti] = Sw[0][c*TT + t];
            v1[ti] = Sw[1][c*TT + t];
            v2[ti] = Sw[2][c*TT + t];
        }
        #pragma unroll
        for (int oi = 0; oi < 4; ++oi) {
            int o = ob + 16*oi;
            float w0 = WmT[(c       )*64 + o];
            float w1 = WmT[(CC  + c )*64 + o];
            float w2 = WmT[(2*CC + c)*64 + o];
            #pragma unroll
            for (int ti = 0; ti < 3; ++ti) {
                acc[oi][ti] += v0[ti]*w0 + v1[ti]*w1 + v2[ti]*w2;
            }
        }
    }

    #pragma unroll
    for (int oi = 0; oi < 4; ++oi) {
        int o = ob + 16*oi;
        #pragma unroll
        for (int ti = 0; ti < 3; ++ti) {
            int t = tq + 4*ti;
            out[((b*CC + o)*NN + n)*TT + t] = acc[oi][ti];
        }
    }
}

// ---------------------------------------------------------------------------
extern "C" void kernel_launch(void* const* d_in, const int* in_sizes, int n_in,
                              void* d_out, int out_size, void* d_ws, size_t ws_size,
                              hipStream_t stream) {
    const float* x   = (const float*)d_in[0];
    const float* adj = (const float*)d_in[1];
    const float* W   = (const float*)d_in[2];
    const float* a1  = (const float*)d_in[3];
    const float* a2  = (const float*)d_in[4];
    const float* Wg  = (const float*)d_in[5];
    const float* bg  = (const float*)d_in[6];
    const float* Wm  = (const float*)d_in[7];
    const float* bm  = (const float*)d_in[8];
    float* out = (float*)d_out;

    char* ws = (char*)d_ws;
    size_t off = 0;
    auto alloc = [&](size_t bytes) -> void* {
        void* p = ws + off;
        off += (bytes + 255) & ~(size_t)255;
        return p;
    };

    uint_t* maskbits = (uint_t*)alloc((size_t)512 * 16 * 4);                // 32 KB
    float* p1   = (float*)alloc(HH*CC * sizeof(float));
    float* p2   = (float*)alloc(HH*CC * sizeof(float));
    float* WmT  = (float*)alloc(3*CC*CC * sizeof(float));
    ushort_t* WgB = (ushort_t*)alloc((size_t)FF*HF * 2);
    float* xT   = (float*)alloc((size_t)NNODE * CT * sizeof(float));        // 12.3 MB
    ushort_t* Wh   = (ushort_t*)alloc((size_t)NROWS * FF * 2);              // 24.6 MB
    ushort_t* WhT  = (ushort_t*)alloc((size_t)NBHT * 64 * 512 * 2);         // 25.2 MB
    ushort_t* hprB = (ushort_t*)alloc((size_t)NNODE * NBT * FF * 2);        // 24.6 MB
    float* e1   = (float*)alloc((size_t)NROWS * sizeof(float));
    float* e2   = (float*)alloc((size_t)NROWS * sizeof(float));
    float* h1   = (float*)alloc((size_t)NNODE * CT * sizeof(float));        // 12.3 MB
    (void)ws_size;

    k01_setup<<<146, 256, 0, stream>>>(adj, W, a1, a2, Wm, Wg,
                                       maskbits, p1, p2, WmT, WgB);
    k6_xt    <<<256, 256, 0, stream>>>(x, xT);

    // layer 1
    k2_wh_e <<<NNODE/4, 256, 0, stream>>>(xT, W, p1, p2, Wh, e1, e2);
    k2t     <<<NBHT*2,  256, 0, stream>>>(Wh, WhT);
    k3_attn <<<NBHT*2,  256, 0, stream>>>(WhT, e1, e2, maskbits, hprB);
    k4_mfma <<<NNODE/4, 256, 0, stream>>>(hprB, WgB, bg, xT, h1);

    // layer 2
    k2_wh_e <<<NNODE/4, 256, 0, stream>>>(h1, W, p1, p2, Wh, e1, e2);
    k2t     <<<NBHT*2,  256, 0, stream>>>(Wh, WhT);
    k3_attn <<<NBHT*2,  256, 0, stream>>>(WhT, e1, e2, maskbits, hprB);

    // fused layer-2 mix + final
    k45_fused<<<NNODE/4, 256, 0, stream>>>(hprB, WgB, bg, xT, h1, WmT, bm, out);
}

// Round 12
// 322.416 us; speedup vs baseline: 2.5607x; 1.0665x over previous
//
#include <hip/hip_runtime.h>
#include <hip/hip_bf16.h>
#include <math.h>

#define BB 8
#define CC 64
#define NN 500
#define TT 12
#define HH 4
#define FF 64
#define CT (CC*TT)      // 768
#define HF (HH*FF)      // 256
#define NBT (HH*TT)     // 48
#define NBHT (BB*NBT)   // 384
#define NROWS (BB*HH*TT*NN)  // 192000
#define NNODE (BB*NN)   // 4000
#define BSR 200         // k45 LDS row stride (ushorts): bank-spread verified

typedef unsigned short ushort_t;
typedef unsigned int uint_t;
typedef __attribute__((ext_vector_type(8))) short short8;
typedef __attribute__((ext_vector_type(4))) float floatx4;

static __device__ __forceinline__ ushort_t f2bf(float v) {
    __hip_bfloat16 h = __float2bfloat16(v);
    ushort_t u;
    __builtin_memcpy(&u, &h, 2);
    return u;
}

// pack two f32 -> packed bf16 (lo = a, hi = b), RNE (hw v_cvt_pk on gfx950)
static __device__ __forceinline__ uint_t pkbf(float a, float b) {
    __hip_bfloat162 h = __float22bfloat162_rn(make_float2(a, b));
    uint_t u;
    __builtin_memcpy(&u, &h, 4);
    return u;
}

// ---------------------------------------------------------------------------
// K01: setup.  Blocks [0,32): bitmask[512][16 dwords]: bit k of row n =
// (adj+I)>0, zero-padded.  Blocks [32,145): p1/p2 folds, WmB=bf16(Wm),
// WgB=bf16(Wg).
// ---------------------------------------------------------------------------
__global__ __launch_bounds__(256) void k01_setup(const float* __restrict__ adj,
                                                 const float* __restrict__ W,
                                                 const float* __restrict__ a1,
                                                 const float* __restrict__ a2,
                                                 const float* __restrict__ Wm,
                                                 const float* __restrict__ Wg,
                                                 uint_t* __restrict__ maskbits,
                                                 float* __restrict__ p1,
                                                 float* __restrict__ p2,
                                                 ushort_t* __restrict__ WmB,
                                                 ushort_t* __restrict__ WgB) {
    int blk = blockIdx.x;
    if (blk < 32) {
        int idx = blk * 256 + threadIdx.x;   // < 512*16
        int n = idx >> 4, j = idx & 15;      // dword j covers m = j*32..+31
        uint_t v = 0;
        if (n < NN) {
            int m0 = j * 32;
            for (int i = 0; i < 32; ++i) {
                int m = m0 + i;
                bool p = (m < NN) && (adj[n*NN + m] > 0.f || m == n);
                v |= (p ? 1u : 0u) << i;
            }
        }
        maskbits[idx] = v;
        return;
    }
    int idx = (blk - 32) * 256 + threadIdx.x;
    if (idx < HH*CC) {
        int h = idx / CC, c = idx % CC;
        float s1 = 0.f, s2 = 0.f;
        for (int f = 0; f < FF; ++f) {
            float w = W[(h*CC + c)*FF + f];
            s1 += w * a1[h*FF + f];
            s2 += w * a2[h*FF + f];
        }
        p1[idx] = s1; p2[idx] = s2;
    }
    int j = idx - HH*CC;
    if (j >= 0 && j < CC*3*CC) {          // 12288: WmB = bf16(Wm), [o][192]
        WmB[j] = f2bf(Wm[j]);
    }
    int j2 = idx - (HH*CC + CC*3*CC);
    if (j2 >= 0 && j2 < FF*HF) {
        WgB[j2] = f2bf(Wg[j2]);
    }
}

// ---------------------------------------------------------------------------
// K6: transpose x [B,C,N,T] -> xT [(b*N+n)*768 + c*12 + t] (node-major).
// ---------------------------------------------------------------------------
__global__ __launch_bounds__(256) void k6_xt(const float* __restrict__ x,
                                             float* __restrict__ xT) {
    __shared__ float tile[16*776];   // 49664 B
    int b  = blockIdx.x >> 5;
    int n0 = (blockIdx.x & 31) * 16;
    for (int idx = threadIdx.x; idx < CC*16*TT; idx += 256) {
        int c   = idx / (16*TT);
        int rem = idx % (16*TT);
        int nl  = rem / TT;
        int t   = rem % TT;
        int n   = n0 + nl;
        if (n < NN)
            tile[nl*776 + c*TT + t] = x[((b*CC + c)*NN + n)*TT + t];
    }
    __syncthreads();
    for (int idx = threadIdx.x; idx < 16*CT; idx += 256) {
        int nl = idx / CT;
        int j  = idx % CT;
        int n  = n0 + nl;
        if (n < NN)
            xT[(size_t)(b*NN + n)*CT + j] = tile[nl*776 + j];
    }
}

// ---------------------------------------------------------------------------
// K2: Wh[bht][n][f] (bf16) = sum_c h[node][c,t] * W[h,c,f]; e1/e2 via p1/p2.
// f-PAIR remap -> packed dword Wh stores.
// ---------------------------------------------------------------------------
__global__ __launch_bounds__(256) void k2_wh_e(const float* __restrict__ hin,
                                               const float* __restrict__ W,
                                               const float* __restrict__ p1,
                                               const float* __restrict__ p2,
                                               ushort_t* __restrict__ Wh,
                                               float* __restrict__ e1,
                                               float* __restrict__ e2) {
    __shared__ float hL[4][CT];
    int wid  = threadIdx.x >> 6;
    int lane = threadIdx.x & 63;
    int gidx = blockIdx.x * 4 + wid;
    int b = gidx / NN, n = gidx % NN;

    {
        const float4* src = (const float4*)(hin + (size_t)gidx * CT);
        float4* dst = (float4*)hL[wid];
        for (int i = lane; i < CT/4; i += 64) dst[i] = src[i];
    }
    __syncthreads();

    const float*  hLw = hL[wid];
    const float4* h4  = (const float4*)hLw;
    int h  = lane >> 4;
    int fb = lane & 15;

    float acc[4][TT];
    #pragma unroll
    for (int q = 0; q < 4; ++q)
        #pragma unroll
        for (int t = 0; t < TT; ++t) acc[q][t] = 0.f;

    for (int c = 0; c < CC; ++c) {
        float4 v0 = h4[c*3+0], v1 = h4[c*3+1], v2 = h4[c*3+2];
        float hv[12] = {v0.x,v0.y,v0.z,v0.w, v1.x,v1.y,v1.z,v1.w,
                        v2.x,v2.y,v2.z,v2.w};
        const float* Wc = W + (h*CC + c)*FF;
        float2 wA = *(const float2*)&Wc[2*fb];
        float2 wB = *(const float2*)&Wc[2*fb + 32];
        #pragma unroll
        for (int t = 0; t < TT; ++t) {
            acc[0][t] += hv[t]*wA.x;
            acc[1][t] += hv[t]*wA.y;
            acc[2][t] += hv[t]*wB.x;
            acc[3][t] += hv[t]*wB.y;
        }
    }
    #pragma unroll
    for (int t = 0; t < TT; ++t) {
        size_t row = ((size_t)((b*HH + h)*TT + t)*NN + n)*FF;
        *(uint_t*)&Wh[row + 2*fb]      = pkbf(acc[0][t], acc[1][t]);
        *(uint_t*)&Wh[row + 2*fb + 32] = pkbf(acc[2][t], acc[3][t]);
    }

    int t2 = lane & 15;
    if (t2 < TT) {
        int h2 = lane >> 4;
        float s1 = 0.f, s2 = 0.f;
        for (int c = 0; c < CC; ++c) {
            float v = hLw[c*TT + t2];
            s1 += v * p1[h2*CC + c];
            s2 += v * p2[h2*CC + c];
        }
        int idx = ((b*HH + h2)*TT + t2)*NN + n;
        e1[idx] = s1;
        e2[idx] = s2;
    }
}

// ---------------------------------------------------------------------------
// K2T: Wh[bht][n<500][64] -> WhT[bht][f=64][m=512] bf16, m>=500 zeroed.
// ---------------------------------------------------------------------------
__global__ __launch_bounds__(256) void k2t(const ushort_t* __restrict__ Wh,
                                           ushort_t* __restrict__ WhT) {
    __shared__ ushort_t tile[32*512];     // 32 KB
    int wid  = threadIdx.x >> 6;
    int lane = threadIdx.x & 63;
    int bht  = blockIdx.x >> 1;
    int fh   = blockIdx.x & 1;            // f half: f0 = fh*32
    const ushort_t* src = Wh + (size_t)bht * NN * FF + fh*32;

    for (int task = wid; task < 32; task += 4) {
        int i  = task >> 2;               // m-block of 64 (0..7)
        int fo = task & 3;                // f-octet within half (0..3)
        int m  = i*64 + lane;
        short8 v = {0,0,0,0,0,0,0,0};
        if (m < NN) v = *(const short8*)(src + m*FF + fo*8);
        #pragma unroll
        for (int j = 0; j < 8; ++j)
            tile[(fo*8 + j)*512 + m] = (ushort_t)v[j];
    }
    __syncthreads();

    ushort_t* dst = WhT + (size_t)bht * 64 * 512 + (size_t)fh*32*512;
    for (int f = wid; f < 32; f += 4) {
        short8 v = *(const short8*)&tile[f*512 + lane*8];
        *(short8*)(dst + f*512 + lane*8) = v;
    }
}

// ---------------------------------------------------------------------------
// K3: attention PV via MFMA (R11 structure, unchanged — measured winner).
// 4 tiles/wave share each scattered B-load; LDS bitmask rows (stride 17).
// ---------------------------------------------------------------------------
__global__ __launch_bounds__(256, 3) void k3_attn(const ushort_t* __restrict__ WhT,
                                                  const float* __restrict__ e1,
                                                  const float* __restrict__ e2,
                                                  const uint_t* __restrict__ maskbits,
                                                  ushort_t* __restrict__ hprB) {
    __shared__ float  e2s[512];           // 2 KB
    __shared__ uint_t mks[256*17];        // 17408 B
    int tid  = threadIdx.x;
    int wid  = tid >> 6;
    int lane = tid & 63;
    int bht  = blockIdx.x >> 1;
    int half = blockIdx.x & 1;
    int b    = bht / NBT;
    int ht   = bht % NBT;

    const float* e1p = e1 + (size_t)bht * NN;
    const float* e2p = e2 + (size_t)bht * NN;
    const ushort_t* WT = WhT + (size_t)bht * 64 * 512;
    const float L2E = 1.4426950408889634f;

    {
        int i = tid;
        e2s[i] = (i < NN) ? e2p[i] * L2E : 0.f;
        i = tid + 256;
        e2s[i] = (i < NN) ? e2p[i] * L2E : 0.f;
    }
    for (int i = tid; i < 256*16; i += 256) {
        int rl = i >> 4, dw = i & 15;
        mks[rl*17 + dw] = maskbits[(half*256 + rl)*16 + dw];
    }
    __syncthreads();

    int quad = lane >> 4;                 // 0..3
    int r    = lane & 15;                 // A-row / C-col

    const short8 ONES = {0x3F80,0x3F80,0x3F80,0x3F80,
                         0x3F80,0x3F80,0x3F80,0x3F80}; // bf16 1.0 x8

    float e1v[4];
    #pragma unroll
    for (int u = 0; u < 4; ++u) {
        int nrow = half*256 + (wid*4 + u)*16 + r;
        e1v[u] = ((nrow < NN) ? e1p[nrow] : 0.f) * L2E;
    }
    int rl0 = wid*64 + r;

    const ushort_t* WTr = WT + (size_t)r * 512;

    floatx4 C[4][4];
    floatx4 Cs[4];
    #pragma unroll
    for (int u = 0; u < 4; ++u) {
        Cs[u] = (floatx4){0.f,0.f,0.f,0.f};
        #pragma unroll
        for (int ft = 0; ft < 4; ++ft) C[u][ft] = (floatx4){0.f,0.f,0.f,0.f};
    }

    #pragma unroll
    for (int ki = 0; ki < 16; ++ki) {
        int kb = ki*32 + quad*8;

        short8 b0 = *(const short8*)(WTr + 0*8192 + kb);
        short8 b1 = *(const short8*)(WTr + 1*8192 + kb);
        short8 b2 = *(const short8*)(WTr + 2*8192 + kb);
        short8 b3 = *(const short8*)(WTr + 3*8192 + kb);

        float4 ea = *(const float4*)&e2s[kb];
        float4 eb = *(const float4*)&e2s[kb + 4];
        float ev[8] = {ea.x,ea.y,ea.z,ea.w, eb.x,eb.y,eb.z,eb.w};

        #pragma unroll
        for (int u = 0; u < 4; ++u) {
            uint_t md    = mks[(rl0 + u*16)*17 + ki];
            uint_t mbits = md >> (quad*8);
            union { uint_t w[4]; short8 s; } av;
            #pragma unroll
            for (int p = 0; p < 4; ++p) {
                float s0 = e1v[u] + ev[2*p];
                float s1 = e1v[u] + ev[2*p+1];
                float g0 = fmaxf(s0, 0.2f*s0);
                float g1 = fmaxf(s1, 0.2f*s1);
                float x0 = __builtin_amdgcn_exp2f(g0);
                float x1 = __builtin_amdgcn_exp2f(g1);
                x0 = (mbits & (1u << (2*p)))     ? x0 : 0.f;
                x1 = (mbits & (1u << (2*p + 1))) ? x1 : 0.f;
                av.w[p] = pkbf(x0, x1);
            }
            C[u][0] = __builtin_amdgcn_mfma_f32_16x16x32_bf16(av.s, b0, C[u][0], 0, 0, 0);
            C[u][1] = __builtin_amdgcn_mfma_f32_16x16x32_bf16(av.s, b1, C[u][1], 0, 0, 0);
            C[u][2] = __builtin_amdgcn_mfma_f32_16x16x32_bf16(av.s, b2, C[u][2], 0, 0, 0);
            C[u][3] = __builtin_amdgcn_mfma_f32_16x16x32_bf16(av.s, b3, C[u][3], 0, 0, 0);
            Cs[u]   = __builtin_amdgcn_mfma_f32_16x16x32_bf16(av.s, ONES, Cs[u], 0, 0, 0);
        }
    }

    #pragma unroll
    for (int u = 0; u < 4; ++u) {
        int n0 = half*256 + (wid*4 + u)*16;
        #pragma unroll
        for (int reg = 0; reg < 4; ++reg) {
            int n = n0 + quad*4 + reg;
            if (n < NN) {
                float inv = 1.0f / Cs[u][reg];
                size_t base = ((size_t)(b*NN + n)*NBT + ht)*FF;
                #pragma unroll
                for (int ft = 0; ft < 4; ++ft) {
                    float v = C[u][ft][reg] * inv;
                    v = v > 0.f ? v : __expf(v) - 1.f;
                    hprB[base + ft*16 + r] = f2bf(v);
                }
            }
        }
    }
}

// ---------------------------------------------------------------------------
// K4: head-mix 1x1 conv + residual via MFMA.  1 node per WAVE, 1000 blocks.
// ---------------------------------------------------------------------------
__global__ __launch_bounds__(256) void k4_mfma(const ushort_t* __restrict__ hprB,
                                               const ushort_t* __restrict__ WgB,
                                               const float* __restrict__ bg,
                                               const float* __restrict__ xT,
                                               float* __restrict__ hnext) {
    int wid  = threadIdx.x >> 6;
    int lane = threadIdx.x & 63;
    int quad = lane >> 4;
    int r    = lane & 15;

    short8 Afr[4][8];
    #pragma unroll
    for (int ot = 0; ot < 4; ++ot)
        #pragma unroll
        for (int kc = 0; kc < 8; ++kc)
            Afr[ot][kc] = *(const short8*)(WgB + (size_t)(ot*16 + r)*HF + kc*32 + quad*8);

    float4 bgv[4];
    #pragma unroll
    for (int ot = 0; ot < 4; ++ot)
        bgv[ot] = *(const float4*)(bg + ot*16 + quad*4);

    int tcl = r < TT ? r : TT-1;

    int node = blockIdx.x*4 + wid;
    const ushort_t* P = hprB + (size_t)node * (NBT*FF);

    floatx4 C[4];
    #pragma unroll
    for (int ot = 0; ot < 4; ++ot) C[ot] = (floatx4){0.f,0.f,0.f,0.f};

    #pragma unroll
    for (int kc = 0; kc < 8; ++kc) {
        int k = kc*32 + quad*8;
        int h = k >> 6, f0 = k & 63;
        short8 bfr = *(const short8*)(P + (h*TT + tcl)*FF + f0);
        #pragma unroll
        for (int ot = 0; ot < 4; ++ot)
            C[ot] = __builtin_amdgcn_mfma_f32_16x16x32_bf16(Afr[ot][kc], bfr, C[ot], 0, 0, 0);
    }

    if (r < TT) {
        float* hout = hnext + (size_t)node * CT;
        const float* xp = xT + (size_t)node * CT;
        #pragma unroll
        for (int ot = 0; ot < 4; ++ot) {
            #pragma unroll
            for (int reg = 0; reg < 4; ++reg) {
                int o = ot*16 + quad*4 + reg;
                float v = C[ot][reg] + bgv[ot][reg];
                hout[o*TT + r] = 0.05f*xp[o*TT + r] + 0.95f*v;
            }
        }
    }
}

// ---------------------------------------------------------------------------
// K45: fused layer-2 head-mix + final mix, BOTH via MFMA.  1 node/wave.
// Phase 1 (k4 body): h2 = 0.05x + 0.95(Wg @ hpr + bg) -> bf16 LDS [t][c]
// section 2 (packed dword writes, <=2-way banks).  x,h1 staged bf16 into
// sections 0,1.  Phase 2: out = bm + Wm(bf16) @ [x|h1|h2]: A-frags from
// WmB (16B loads), B-frags ds_read_b128 from the [t][BSR] rows.  All LDS
// wave-private -> no barriers (compiler inserts lgkm waits).
// ---------------------------------------------------------------------------
__global__ __launch_bounds__(256) void k45_fused(const ushort_t* __restrict__ hprB,
                                                 const ushort_t* __restrict__ WgB,
                                                 const float* __restrict__ bg,
                                                 const float* __restrict__ xT,
                                                 const float* __restrict__ h1,
                                                 const ushort_t* __restrict__ WmB,
                                                 const float* __restrict__ bm,
                                                 float* __restrict__ out) {
    __shared__ ushort_t Bs[4][TT*BSR];    // 4 x 4800 B = 19200 B
    int wid  = threadIdx.x >> 6;
    int lane = threadIdx.x & 63;
    int quad = lane >> 4;
    int r    = lane & 15;

    int node = blockIdx.x*4 + wid;
    int b = node / NN, n = node % NN;
    ushort_t* Bw = Bs[wid];

    {   // stage x, h1 -> bf16 [t][c] (lane = channel c)
        const float* xp = xT + (size_t)node*CT + lane*TT;
        const float* hp = h1 + (size_t)node*CT + lane*TT;
        float4 x0 = *(const float4*)(xp);
        float4 x1 = *(const float4*)(xp + 4);
        float4 x2 = *(const float4*)(xp + 8);
        float4 g0 = *(const float4*)(hp);
        float4 g1 = *(const float4*)(hp + 4);
        float4 g2 = *(const float4*)(hp + 8);
        float xa[12] = {x0.x,x0.y,x0.z,x0.w, x1.x,x1.y,x1.z,x1.w,
                        x2.x,x2.y,x2.z,x2.w};
        float ha[12] = {g0.x,g0.y,g0.z,g0.w, g1.x,g1.y,g1.z,g1.w,
                        g2.x,g2.y,g2.z,g2.w};
        #pragma unroll
        for (int t = 0; t < TT; ++t) {
            Bw[t*BSR + lane]      = f2bf(xa[t]);
            Bw[t*BSR + 64 + lane] = f2bf(ha[t]);
        }
    }

    // ---- phase 1 (k4 body): h2 via MFMA -> Bs section 2 ----
    {
        short8 Afr[4][8];
        #pragma unroll
        for (int ot = 0; ot < 4; ++ot)
            #pragma unroll
            for (int kc = 0; kc < 8; ++kc)
                Afr[ot][kc] = *(const short8*)(WgB + (size_t)(ot*16 + r)*HF + kc*32 + quad*8);
        float4 bgv[4];
        #pragma unroll
        for (int ot = 0; ot < 4; ++ot)
            bgv[ot] = *(const float4*)(bg + ot*16 + quad*4);

        int tcl = r < TT ? r : TT-1;
        const ushort_t* P = hprB + (size_t)node * (NBT*FF);

        floatx4 C[4];
        #pragma unroll
        for (int ot = 0; ot < 4; ++ot) C[ot] = (floatx4){0.f,0.f,0.f,0.f};
        #pragma unroll
        for (int kc = 0; kc < 8; ++kc) {
            int k = kc*32 + quad*8;
            int h = k >> 6, f0 = k & 63;
            short8 bfr = *(const short8*)(P + (h*TT + tcl)*FF + f0);
            #pragma unroll
            for (int ot = 0; ot < 4; ++ot)
                C[ot] = __builtin_amdgcn_mfma_f32_16x16x32_bf16(Afr[ot][kc], bfr, C[ot], 0, 0, 0);
        }

        if (r < TT) {
            const float* xp = xT + (size_t)node * CT;
            #pragma unroll
            for (int ot = 0; ot < 4; ++ot) {
                #pragma unroll
                for (int rp = 0; rp < 4; rp += 2) {
                    int o = ot*16 + quad*4 + rp;
                    float v0 = C[ot][rp]   + bgv[ot][rp];
                    float v1 = C[ot][rp+1] + bgv[ot][rp+1];
                    float h20 = 0.05f*xp[o*TT + r]       + 0.95f*v0;
                    float h21 = 0.05f*xp[(o+1)*TT + r]   + 0.95f*v1;
                    *(uint_t*)&Bw[r*BSR + 128 + o] = pkbf(h20, h21);
                }
            }
        }
    }

    // ---- phase 2 (k5 body): out = bm + WmB @ [x|h1|h2] via MFMA ----
    {
        short8 Am[4][6];
        #pragma unroll
        for (int ot = 0; ot < 4; ++ot)
            #pragma unroll
            for (int kc = 0; kc < 6; ++kc)
                Am[ot][kc] = *(const short8*)(WmB + (size_t)(ot*16 + r)*(3*CC) + kc*32 + quad*8);

        int trd = r < TT ? r : TT-1;      // clamp (rows 12..15 unused)
        floatx4 C2[4];
        #pragma unroll
        for (int ot = 0; ot < 4; ++ot) C2[ot] = (floatx4){0.f,0.f,0.f,0.f};
        #pragma unroll
        for (int kc = 0; kc < 6; ++kc) {
            short8 bfr = *(const short8*)&Bw[trd*BSR + kc*32 + quad*8];
            #pragma unroll
            for (int ot = 0; ot < 4; ++ot)
                C2[ot] = __builtin_amdgcn_mfma_f32_16x16x32_bf16(Am[ot][kc], bfr, C2[ot], 0, 0, 0);
        }

        if (r < TT) {
            #pragma unroll
            for (int ot = 0; ot < 4; ++ot) {
                float4 bmv = *(const float4*)(bm + ot*16 + quad*4);
                #pragma unroll
                for (int reg = 0; reg < 4; ++reg) {
                    int o = ot*16 + quad*4 + reg;
                    out[((size_t)(b*CC + o)*NN + n)*TT + r] = C2[ot][reg] + bmv[reg];
                }
            }
        }
    }
}

// ---------------------------------------------------------------------------
extern "C" void kernel_launch(void* const* d_in, const int* in_sizes, int n_in,
                              void* d_out, int out_size, void* d_ws, size_t ws_size,
                              hipStream_t stream) {
    const float* x   = (const float*)d_in[0];
    const float* adj = (const float*)d_in[1];
    const float* W   = (const float*)d_in[2];
    const float* a1  = (const float*)d_in[3];
    const float* a2  = (const float*)d_in[4];
    const float* Wg  = (const float*)d_in[5];
    const float* bg  = (const float*)d_in[6];
    const float* Wm  = (const float*)d_in[7];
    const float* bm  = (const float*)d_in[8];
    float* out = (float*)d_out;

    char* ws = (char*)d_ws;
    size_t off = 0;
    auto alloc = [&](size_t bytes) -> void* {
        void* p = ws + off;
        off += (bytes + 255) & ~(size_t)255;
        return p;
    };

    uint_t* maskbits = (uint_t*)alloc((size_t)512 * 16 * 4);                // 32 KB
    float* p1   = (float*)alloc(HH*CC * sizeof(float));
    float* p2   = (float*)alloc(HH*CC * sizeof(float));
    ushort_t* WmB = (ushort_t*)alloc((size_t)CC*3*CC * 2);                  // 24.6 KB
    ushort_t* WgB = (ushort_t*)alloc((size_t)FF*HF * 2);
    float* xT   = (float*)alloc((size_t)NNODE * CT * sizeof(float));        // 12.3 MB
    ushort_t* Wh   = (ushort_t*)alloc((size_t)NROWS * FF * 2);              // 24.6 MB
    ushort_t* WhT  = (ushort_t*)alloc((size_t)NBHT * 64 * 512 * 2);         // 25.2 MB
    ushort_t* hprB = (ushort_t*)alloc((size_t)NNODE * NBT * FF * 2);        // 24.6 MB
    float* e1   = (float*)alloc((size_t)NROWS * sizeof(float));
    float* e2   = (float*)alloc((size_t)NROWS * sizeof(float));
    float* h1   = (float*)alloc((size_t)NNODE * CT * sizeof(float));        // 12.3 MB
    (void)ws_size;

    k01_setup<<<145, 256, 0, stream>>>(adj, W, a1, a2, Wm, Wg,
                                       maskbits, p1, p2, WmB, WgB);
    k6_xt    <<<256, 256, 0, stream>>>(x, xT);

    // layer 1
    k2_wh_e <<<NNODE/4, 256, 0, stream>>>(xT, W, p1, p2, Wh, e1, e2);
    k2t     <<<NBHT*2,  256, 0, stream>>>(Wh, WhT);
    k3_attn <<<NBHT*2,  256, 0, stream>>>(WhT, e1, e2, maskbits, hprB);
    k4_mfma <<<NNODE/4, 256, 0, stream>>>(hprB, WgB, bg, xT, h1);

    // layer 2
    k2_wh_e <<<NNODE/4, 256, 0, stream>>>(h1, W, p1, p2, Wh, e1, e2);
    k2t     <<<NBHT*2,  256, 0, stream>>>(Wh, WhT);
    k3_attn <<<NBHT*2,  256, 0, stream>>>(WhT, e1, e2, maskbits, hprB);

    // fused layer-2 mix + final (both matmuls on MFMA)
    k45_fused<<<NNODE/4, 256, 0, stream>>>(hprB, WgB, bg, xT, h1, WmB, bm, out);
}